// Round 12
// baseline (52.438 us; speedup 1.0000x reference)
//
#include <hip/hip_runtime.h>

// Diagonal depthwise conv, derived from the reference:
//   View x as X[R][W], R = B*C*H = 131072, W = 256.
//   out[r][w] = bias[c] + sum_k weight[c][k] * X[(r+2-k) mod R][w+k-2]
//   where c = (r / H) % C, column OOB -> 0, row index wraps mod R
//   (torch.roll on the fully-flattened tensor wraps across h/c/b).
//
// Round-11 (= round-8 with ROWS=4: occupancy/ILP balance point):
//  * Round-10 A/B: nt dense stores beat cached dense stores (48.0 vs 51.9,
//    FETCH ~same) -> nt's win is L2-side; keep __builtin_nontemporal_store.
//  * Occupancy trend (61%/45%/37% at 16K/8K/4K blocks) says wave residency
//    is the remaining lever; ROWS=4 doubles blocks vs round 8 while keeping
//    the 2-dwordx4 window (1.0 load-inst/output, 16 independent loads).
//  * Window F[0..7] = x[base-2 .. base+5] via two 16B loads, clamp-remap
//    at the two global-edge lanes (round-8 fix).

#define WIDTH 256
#define RTOT  131072            // 8 * 64 * 256
#define NTOT  (RTOT * WIDTH)    // 33,554,432 (fits int)
#define NCH   64
#define KS    5
#define ROWS  4                 // output rows per thread

typedef float f32x4 __attribute__((ext_vector_type(4)));
typedef f32x4 f32x4_a8 __attribute__((aligned(8)));   // 8B-aligned 16B load

__global__ __launch_bounds__(256) void diag_dwconv_kernel(
    const float* __restrict__ x,
    const float* __restrict__ wgt,    // [C][1][KS] flat
    const float* __restrict__ bias,   // [C]
    float* __restrict__ out)
{
    int v  = blockIdx.x * blockDim.x + threadIdx.x;  // [0, RTOT/ROWS * 64)
    int rq = (v >> 6) << 2;          // base output row (wave-uniform, 4-aligned)
    int w0 = (v & 63) << 2;          // 4-col segment; lanes cover one full row
    int c  = __builtin_amdgcn_readfirstlane((rq >> 8) & (NCH - 1));

    float wv[KS];
    #pragma unroll
    for (int k = 0; k < KS; ++k) wv[k] = wgt[c * KS + k];   // scalar loads
    float b = bias[c];

    float acc[ROWS][4];
    #pragma unroll
    for (int i = 0; i < ROWS; ++i)
        #pragma unroll
        for (int jj = 0; jj < 4; ++jj) acc[i][jj] = b;

    bool edgeL = (w0 == 0);           // lane 0 of the wave
    bool edgeR = (w0 == WIDTH - 4);   // lane 63 of the wave

    #pragma unroll
    for (int j = -2; j <= ROWS + 1; ++j) {    // source row rq + j (8 rows)
        int rk = rq + j;
        if (rk < 0)          rk += RTOT;      // wrap across flat tensor
        else if (rk >= RTOT) rk -= RTOT;
        int base = rk * WIDTH + w0;

        int aoff = base - 2;
        bool clampA = (aoff < 0);             // only rk==0 && w0==0
        if (clampA) aoff = 0;
        int boff = base + 2;
        bool clampB = (boff > NTOT - 4);      // only rk==RTOT-1 && w0==252
        if (clampB) boff = NTOT - 4;

        f32x4 A = *reinterpret_cast<const f32x4_a8*>(x + aoff);  // w0-2 .. w0+1
        f32x4 B = *reinterpret_cast<const f32x4_a8*>(x + boff);  // w0+2 .. w0+5

        float F[8] = { A.x, A.y, A.z, A.w, B.x, B.y, B.z, B.w };
        // clamp remap: clamped A holds cols 0..3 -> F[2]=col0, F[3]=col1;
        //              clamped B holds cols 252..255 -> F[4]=col254, F[5]=col255
        if (clampA) { F[2] = A.x; F[3] = A.y; }
        if (clampB) { F[4] = B.z; F[5] = B.w; }
        if (edgeL)  { F[0] = 0.f; F[1] = 0.f; }  // cols < 0 contribute 0
        if (edgeR)  { F[6] = 0.f; F[7] = 0.f; }  // cols >= WIDTH contribute 0

        #pragma unroll
        for (int i = 0; i < ROWS; ++i) {      // output row rq + i
            int k = i - j + 2;                // tap index (compile-time const)
            if (k >= 0 && k < KS) {
                #pragma unroll
                for (int jj = 0; jj < 4; ++jj)
                    acc[i][jj] = fmaf(wv[k], F[jj + k], acc[i][jj]);
            }
        }
    }

    #pragma unroll
    for (int i = 0; i < ROWS; ++i) {
        int ob = (rq + i) * WIDTH + w0;
        f32x4 o = { acc[i][0], acc[i][1], acc[i][2], acc[i][3] };
        __builtin_nontemporal_store(o, reinterpret_cast<f32x4*>(out + ob));
    }
}

extern "C" void kernel_launch(void* const* d_in, const int* in_sizes, int n_in,
                              void* d_out, int out_size, void* d_ws, size_t ws_size,
                              hipStream_t stream) {
    const float* x    = (const float*)d_in[0];
    const float* wgt  = (const float*)d_in[1];
    const float* bias = (const float*)d_in[2];
    float* out        = (float*)d_out;

    // one thread per 16 outputs (4 rows x 4 cols): 33,554,432 / 16 = 2,097,152
    int threads = 256;
    int blocks  = (out_size / 16 + threads - 1) / threads;   // 8192
    diag_dwconv_kernel<<<blocks, threads, 0, stream>>>(x, wgt, bias, out);
}

// Round 13
// 47.713 us; speedup vs baseline: 1.0990x; 1.0990x over previous
//
#include <hip/hip_runtime.h>

// Diagonal depthwise conv, derived from the reference:
//   View x as X[R][W], R = B*C*H = 131072, W = 256.
//   out[r][w] = bias[c] + sum_k weight[c][k] * X[(r+2-k) mod R][w+k-2]
//   where c = (r / H) % C, column OOB -> 0, row index wraps mod R
//   (torch.roll on the fully-flattened tensor wraps across h/c/b).
//
// Round-12 (ROWS=8 + ALIGNED windows — the untested cell):
//   datapoint matrix: R6 (4 rows, aligned 3-load) 47.5 | R11 (4 rows,
//   unaligned 2-load) 52.4 | R8 (8 rows, unaligned) 48.0.
//   -> unaligned dwordx4 (8B-aligned, straddles 64B lines, ~2x TA
//      transactions) costs ~5 us; deep tile is worth ~4.4 us.
//   This kernel: 8 rows x 4 cols, window as float2+float4+float2 (ALL
//   naturally aligned, no line splits), nt dense stores (R10 A/B: nt wins
//   at L2), scalar weights via readfirstlane.

#define WIDTH 256
#define RTOT  131072            // 8 * 64 * 256
#define NTOT  (RTOT * WIDTH)    // 33,554,432 (fits int)
#define NCH   64
#define KS    5
#define ROWS  8                 // output rows per thread

typedef float f32x4 __attribute__((ext_vector_type(4)));

__global__ __launch_bounds__(256) void diag_dwconv_kernel(
    const float* __restrict__ x,
    const float* __restrict__ wgt,    // [C][1][KS] flat
    const float* __restrict__ bias,   // [C]
    float* __restrict__ out)
{
    int v  = blockIdx.x * blockDim.x + threadIdx.x;  // [0, RTOT/ROWS * 64)
    int rq = (v >> 6) << 3;          // base output row (wave-uniform, 8-aligned)
    int w0 = (v & 63) << 2;          // 4-col segment; lanes cover one full row
    int c  = __builtin_amdgcn_readfirstlane((rq >> 8) & (NCH - 1));

    float wv[KS];
    #pragma unroll
    for (int k = 0; k < KS; ++k) wv[k] = wgt[c * KS + k];   // scalar loads
    float b = bias[c];

    float acc[ROWS][4];
    #pragma unroll
    for (int i = 0; i < ROWS; ++i)
        #pragma unroll
        for (int jj = 0; jj < 4; ++jj) acc[i][jj] = b;

    bool edgeL = (w0 == 0);           // lane 0 of the wave
    bool edgeR = (w0 == WIDTH - 4);   // lane 63 of the wave

    #pragma unroll
    for (int j = -2; j <= ROWS + 1; ++j) {    // source row rq + j (12 rows)
        int rk = rq + j;
        if (rk < 0)          rk += RTOT;      // wrap across flat tensor
        else if (rk >= RTOT) rk -= RTOT;
        int base = rk * WIDTH + w0;

        int loff = base - 2;                  // OOB only if rk==0 && w0==0
        if (loff < 0) loff = 0;               // loaded value fully masked below
        int roff = base + 4;                  // OOB only if rk==RTOT-1 && w0==252
        if (roff > NTOT - 2) roff = NTOT - 2; // loaded value fully masked below

        float2 L = *reinterpret_cast<const float2*>(x + loff);  // w0-2, w0-1 (8B-aligned)
        float4 M = *reinterpret_cast<const float4*>(x + base);  // w0..w0+3  (16B-aligned)
        float2 R = *reinterpret_cast<const float2*>(x + roff);  // w0+4, w0+5 (8B-aligned)

        if (edgeL) { L.x = 0.f; L.y = 0.f; }  // cols < 0 contribute 0
        if (edgeR) { R.x = 0.f; R.y = 0.f; }  // cols >= WIDTH contribute 0

        float F[8] = { L.x, L.y, M.x, M.y, M.z, M.w, R.x, R.y };

        #pragma unroll
        for (int i = 0; i < ROWS; ++i) {      // output row rq + i
            int k = i - j + 2;                // tap index (compile-time const)
            if (k >= 0 && k < KS) {
                #pragma unroll
                for (int jj = 0; jj < 4; ++jj)
                    acc[i][jj] = fmaf(wv[k], F[jj + k], acc[i][jj]);
            }
        }
    }

    #pragma unroll
    for (int i = 0; i < ROWS; ++i) {
        int ob = (rq + i) * WIDTH + w0;
        f32x4 o = { acc[i][0], acc[i][1], acc[i][2], acc[i][3] };
        __builtin_nontemporal_store(o, reinterpret_cast<f32x4*>(out + ob));
    }
}

extern "C" void kernel_launch(void* const* d_in, const int* in_sizes, int n_in,
                              void* d_out, int out_size, void* d_ws, size_t ws_size,
                              hipStream_t stream) {
    const float* x    = (const float*)d_in[0];
    const float* wgt  = (const float*)d_in[1];
    const float* bias = (const float*)d_in[2];
    float* out        = (float*)d_out;

    // one thread per 32 outputs (8 rows x 4 cols): 33,554,432 / 32 = 1,048,576
    int threads = 256;
    int blocks  = (out_size / 32 + threads - 1) / threads;   // 4096
    diag_dwconv_kernel<<<blocks, threads, 0, stream>>>(x, wgt, bias, out);
}

// Round 14
// 47.424 us; speedup vs baseline: 1.1057x; 1.0061x over previous
//
#include <hip/hip_runtime.h>

// Diagonal depthwise conv, derived from the reference:
//   View x as X[R][W], R = B*C*H = 131072, W = 256.
//   out[r][w] = bias[c] + sum_k weight[c][k] * X[(r+2-k) mod R][w+k-2]
//   where c = (r / H) % C, column OOB -> 0, row index wraps mod R
//   (torch.roll on the fully-flattened tensor wraps across h/c/b).
//
// Round-13 (shuffle-halo): one wave spans one full row (64 lanes x 4 cols).
//  * Each lane loads ONLY its own aligned dwordx4 per source row — reads
//    are perfectly dense (16 lines/wave/row vs 48 for window loads; the
//    R6/R8/R11/R12 plateau at ~47.5-48 us shares the 2.8x L1 window
//    amplification; this removes it).
//  * The +-2-column halo comes from the neighbor lane's registers via
//    __shfl_up/__shfl_down(1). Wave edge == row edge, so zeroing the
//    shuffle at lanes 0/63 implements the zero padding exactly. No OOB
//    addresses, no clamps.
//  * ROWS=8 output rows/thread; 12 dense loads + 48 shuffles + 8 nt dense
//    stores per thread (nt wins A/B at L2, round 10).

#define WIDTH 256
#define RTOT  131072            // 8 * 64 * 256
#define NCH   64
#define KS    5
#define ROWS  8                 // output rows per thread

typedef float f32x4 __attribute__((ext_vector_type(4)));

__global__ __launch_bounds__(256) void diag_dwconv_kernel(
    const float* __restrict__ x,
    const float* __restrict__ wgt,    // [C][1][KS] flat
    const float* __restrict__ bias,   // [C]
    float* __restrict__ out)
{
    int v    = blockIdx.x * blockDim.x + threadIdx.x;  // [0, RTOT/ROWS * 64)
    int lane = v & 63;
    int rq   = (v >> 6) << 3;        // base output row (wave-uniform, 8-aligned)
    int w0   = lane << 2;            // 4-col segment; wave spans the full row
    int c    = __builtin_amdgcn_readfirstlane((rq >> 8) & (NCH - 1));

    float wv[KS];
    #pragma unroll
    for (int k = 0; k < KS; ++k) wv[k] = wgt[c * KS + k];   // scalar loads
    float b = bias[c];

    float acc[ROWS][4];
    #pragma unroll
    for (int i = 0; i < ROWS; ++i)
        #pragma unroll
        for (int jj = 0; jj < 4; ++jj) acc[i][jj] = b;

    bool edgeL = (lane == 0);         // cols w0-2,w0-1 are outside the row
    bool edgeR = (lane == 63);        // cols w0+4,w0+5 are outside the row

    #pragma unroll
    for (int j = -2; j <= ROWS + 1; ++j) {    // source row rq + j (12 rows)
        int rk = rq + j;
        if (rk < 0)          rk += RTOT;      // wrap across flat tensor
        else if (rk >= RTOT) rk -= RTOT;

        // one aligned, dense 16B load per lane — never OOB
        float4 M = *reinterpret_cast<const float4*>(x + rk * WIDTH + w0);

        // halo from neighbor lanes' registers
        float pz = __shfl_up(M.z, 1);         // col w0-2 (lane-1's M.z)
        float pw = __shfl_up(M.w, 1);         // col w0-1
        float nx = __shfl_down(M.x, 1);       // col w0+4 (lane+1's M.x)
        float ny = __shfl_down(M.y, 1);       // col w0+5
        if (edgeL) { pz = 0.f; pw = 0.f; }    // zero padding at row start
        if (edgeR) { nx = 0.f; ny = 0.f; }    // zero padding at row end

        float F[8] = { pz, pw, M.x, M.y, M.z, M.w, nx, ny };

        #pragma unroll
        for (int i = 0; i < ROWS; ++i) {      // output row rq + i
            int k = i - j + 2;                // tap index (compile-time const)
            if (k >= 0 && k < KS) {
                #pragma unroll
                for (int jj = 0; jj < 4; ++jj)
                    acc[i][jj] = fmaf(wv[k], F[jj + k], acc[i][jj]);
            }
        }
    }

    #pragma unroll
    for (int i = 0; i < ROWS; ++i) {
        int ob = (rq + i) * WIDTH + w0;
        f32x4 o = { acc[i][0], acc[i][1], acc[i][2], acc[i][3] };
        __builtin_nontemporal_store(o, reinterpret_cast<f32x4*>(out + ob));
    }
}

extern "C" void kernel_launch(void* const* d_in, const int* in_sizes, int n_in,
                              void* d_out, int out_size, void* d_ws, size_t ws_size,
                              hipStream_t stream) {
    const float* x    = (const float*)d_in[0];
    const float* wgt  = (const float*)d_in[1];
    const float* bias = (const float*)d_in[2];
    float* out        = (float*)d_out;

    // one thread per 32 outputs (8 rows x 4 cols): 33,554,432 / 32 = 1,048,576
    int threads = 256;
    int blocks  = (out_size / 32 + threads - 1) / threads;   // 4096
    diag_dwconv_kernel<<<blocks, threads, 0, stream>>>(x, wgt, bias, out);
}